// Round 1
// baseline (510.901 us; speedup 1.0000x reference)
//
#include <hip/hip_runtime.h>

#define HID 256
#define NH 4
#define NEG 0.2f

__device__ __forceinline__ unsigned enc_f(float f) {
    unsigned u = __float_as_uint(f);
    return (u & 0x80000000u) ? ~u : (u | 0x80000000u);
}
__device__ __forceinline__ float dec_f(unsigned k) {
    return (k & 0x80000000u) ? __uint_as_float(k & 0x7FFFFFFFu)
                             : __uint_as_float(~k);
}

// ---- K0: wedot[h] = sum_c We[h*64+c] * att_edge[h*64+c] ----
__global__ void k_wedot(const float* __restrict__ We,
                        const float* __restrict__ att_edge,
                        float* __restrict__ wedot) {
    int t = threadIdx.x;                 // 256 threads, wave t>>6 == head
    float v = We[t] * att_edge[t];
    #pragma unroll
    for (int off = 32; off; off >>= 1) v += __shfl_down(v, off);
    if ((t & 63) == 0) wedot[t >> 6] = v;
}

// ---- K1: in-degree + incoming edge_attr sum ----
__global__ void k_deg(const int* __restrict__ dst,
                      const float* __restrict__ eattr,
                      float* __restrict__ deg, float* __restrict__ loopv,
                      int E) {
    int e = blockIdx.x * 256 + threadIdx.x;
    if (e >= E) return;
    int d = dst[e];
    atomicAdd(&deg[d], 1.0f);
    atomicAdd(&loopv[d], eattr[e]);
}

// ---- K2: xp = x @ W  (+ fused a_s, a_d head reductions) ----
__global__ __launch_bounds__(256) void k_gemm(
    const float* __restrict__ x, const float* __restrict__ W,
    const float* __restrict__ att_src, const float* __restrict__ att_dst,
    float* __restrict__ xp, float* __restrict__ a_s, float* __restrict__ a_d,
    int N) {
    __shared__ float xs[8][HID];
    int t = threadIdx.x;
    int n0 = blockIdx.x * 8;
    #pragma unroll
    for (int r = 0; r < 8; r++) {
        int n = n0 + r;
        xs[r][t] = (n < N) ? x[(size_t)n * HID + t] : 0.0f;
    }
    __syncthreads();
    float acc[8] = {0, 0, 0, 0, 0, 0, 0, 0};
    for (int k = 0; k < HID; k++) {
        float w = W[(size_t)k * HID + t];   // coalesced; W L2-resident
        #pragma unroll
        for (int r = 0; r < 8; r++) acc[r] += xs[r][k] * w;  // LDS broadcast
    }
    float ws_ = att_src[t], wd_ = att_dst[t];  // att_src[h][c] flat == [t]
    int h = t >> 6;
    #pragma unroll
    for (int r = 0; r < 8; r++) {
        int n = n0 + r;
        float vs = acc[r] * ws_, vd = acc[r] * wd_;
        #pragma unroll
        for (int off = 32; off; off >>= 1) {
            vs += __shfl_down(vs, off);
            vd += __shfl_down(vd, off);
        }
        if (n < N) {
            xp[(size_t)n * HID + t] = acc[r];
            if ((t & 63) == 0) {
                a_s[n * NH + h] = vs;
                a_d[n * NH + h] = vd;
            }
        }
    }
}

// ---- K3: logits + leakyReLU + segment max (ordered-int atomicMax) ----
__global__ void k_logits(const int* __restrict__ src, const int* __restrict__ dst,
                         const float* __restrict__ eattr,
                         const float4* __restrict__ a_s4,
                         const float4* __restrict__ a_d4,
                         const float* __restrict__ wedot,
                         const float* __restrict__ deg,
                         const float* __restrict__ loopv,
                         float4* __restrict__ pbuf,
                         unsigned* __restrict__ mkey, int E, int N) {
    int e = blockIdx.x * 256 + threadIdx.x;
    if (e >= E + N) return;
    int s, d;
    float ea;
    if (e < E) {
        s = src[e]; d = dst[e]; ea = eattr[e];
    } else {
        s = d = e - E;
        ea = loopv[d] / fmaxf(deg[d], 1.0f);
    }
    float4 as = a_s4[s], ad = a_d4[d];
    float4 lg;
    lg.x = as.x + ad.x + ea * wedot[0];
    lg.y = as.y + ad.y + ea * wedot[1];
    lg.z = as.z + ad.z + ea * wedot[2];
    lg.w = as.w + ad.w + ea * wedot[3];
    lg.x = lg.x > 0.f ? lg.x : NEG * lg.x;
    lg.y = lg.y > 0.f ? lg.y : NEG * lg.y;
    lg.z = lg.z > 0.f ? lg.z : NEG * lg.z;
    lg.w = lg.w > 0.f ? lg.w : NEG * lg.w;
    pbuf[e] = lg;
    atomicMax(&mkey[d * 4 + 0], enc_f(lg.x));
    atomicMax(&mkey[d * 4 + 1], enc_f(lg.y));
    atomicMax(&mkey[d * 4 + 2], enc_f(lg.z));
    atomicMax(&mkey[d * 4 + 3], enc_f(lg.w));
}

// ---- K4: p = exp(logit - m[dst]); z = segment_sum(p) ----
__global__ void k_pz(const int* __restrict__ dst, float4* __restrict__ pbuf,
                     const unsigned* __restrict__ mkey, float* __restrict__ z,
                     int E, int N) {
    int e = blockIdx.x * 256 + threadIdx.x;
    if (e >= E + N) return;
    int d = (e < E) ? dst[e] : e - E;
    float4 lg = pbuf[e];
    float4 p;
    p.x = __expf(lg.x - dec_f(mkey[d * 4 + 0]));
    p.y = __expf(lg.y - dec_f(mkey[d * 4 + 1]));
    p.z = __expf(lg.z - dec_f(mkey[d * 4 + 2]));
    p.w = __expf(lg.w - dec_f(mkey[d * 4 + 3]));
    pbuf[e] = p;
    atomicAdd(&z[d * 4 + 0], p.x);
    atomicAdd(&z[d * 4 + 1], p.y);
    atomicAdd(&z[d * 4 + 2], p.z);
    atomicAdd(&z[d * 4 + 3], p.w);
}

// ---- K5: out_acc[dst] += alpha * xp[src]  (1 block per edge) ----
__global__ __launch_bounds__(256) void k_scatter(
    const int* __restrict__ src, const int* __restrict__ dst,
    const float* __restrict__ pbuf, const float* __restrict__ z,
    const float* __restrict__ xp, float* __restrict__ outacc, int E, int N) {
    int e = blockIdx.x;
    int t = threadIdx.x;
    int s, d;
    if (e < E) {
        s = src[e]; d = dst[e];
    } else {
        s = d = e - E;
    }
    int h = t >> 6;
    float alpha = pbuf[(size_t)e * 4 + h] / (z[d * 4 + h] + 1e-16f);
    atomicAdd(&outacc[(size_t)d * HID + t], alpha * xp[(size_t)s * HID + t]);
}

// ---- K6: +bias, LayerNorm, +residual, ReLU ----
__global__ __launch_bounds__(256) void k_ln(
    const float* __restrict__ outacc, const float* __restrict__ x,
    const float* __restrict__ bias, const float* __restrict__ gamma,
    const float* __restrict__ beta, float* __restrict__ out, int N) {
    int n = blockIdx.x;
    int t = threadIdx.x;
    float v = outacc[(size_t)n * HID + t] + bias[t];
    float a = v, b = v * v;
    #pragma unroll
    for (int off = 32; off; off >>= 1) {
        a += __shfl_down(a, off);
        b += __shfl_down(b, off);
    }
    __shared__ float s1[4], s2[4];
    if ((t & 63) == 0) {
        s1[t >> 6] = a;
        s2[t >> 6] = b;
    }
    __syncthreads();
    float sum = s1[0] + s1[1] + s1[2] + s1[3];
    float sq = s2[0] + s2[1] + s2[2] + s2[3];
    float mu = sum * (1.0f / HID);
    float var = sq * (1.0f / HID) - mu * mu;
    float hn = (v - mu) * rsqrtf(var + 1e-5f) * gamma[t] + beta[t];
    float o = hn + x[(size_t)n * HID + t];
    out[(size_t)n * HID + t] = o > 0.f ? o : 0.f;
}

extern "C" void kernel_launch(void* const* d_in, const int* in_sizes, int n_in,
                              void* d_out, int out_size, void* d_ws,
                              size_t ws_size, hipStream_t stream) {
    const float* x        = (const float*)d_in[0];
    const int*   ei       = (const int*)d_in[1];
    const float* eattr    = (const float*)d_in[2];
    const float* W        = (const float*)d_in[3];
    const float* att_src  = (const float*)d_in[4];
    const float* att_dst  = (const float*)d_in[5];
    const float* We       = (const float*)d_in[6];
    const float* att_edge = (const float*)d_in[7];
    const float* bias     = (const float*)d_in[8];
    const float* gamma    = (const float*)d_in[9];
    const float* beta     = (const float*)d_in[10];

    int N = in_sizes[0] / HID;
    int E = in_sizes[1] / 2;
    const int* src = ei;
    const int* dst = ei + E;
    float* out = (float*)d_out;

    // workspace layout (floats)
    float* ws     = (float*)d_ws;
    float* xp     = ws;                            // N*HID
    float* pbuf   = xp + (size_t)N * HID;          // (E+N)*4
    float* outacc = pbuf + (size_t)(E + N) * 4;    // N*HID   <- zero from here
    float* a_s    = outacc + (size_t)N * HID;      // N*4
    float* a_d    = a_s + (size_t)N * 4;           // N*4
    float* deg    = a_d + (size_t)N * 4;           // N
    float* loopv  = deg + N;                       // N
    unsigned* mkey = (unsigned*)(loopv + N);       // N*4 (0 == -inf encoded)
    float* z      = (float*)(mkey + (size_t)N * 4);// N*4
    float* wedot  = z + (size_t)N * 4;             // 4

    size_t zero_floats = (size_t)N * HID + 18 * (size_t)N + 4;
    hipMemsetAsync(outacc, 0, zero_floats * sizeof(float), stream);

    k_wedot<<<1, 256, 0, stream>>>(We, att_edge, wedot);
    k_deg<<<(E + 255) / 256, 256, 0, stream>>>(dst, eattr, deg, loopv, E);
    k_gemm<<<(N + 7) / 8, 256, 0, stream>>>(x, W, att_src, att_dst, xp, a_s,
                                            a_d, N);
    int T = E + N;
    k_logits<<<(T + 255) / 256, 256, 0, stream>>>(
        src, dst, eattr, (const float4*)a_s, (const float4*)a_d, wedot, deg,
        loopv, (float4*)pbuf, mkey, E, N);
    k_pz<<<(T + 255) / 256, 256, 0, stream>>>(dst, (float4*)pbuf, mkey, z, E,
                                              N);
    k_scatter<<<T, 256, 0, stream>>>(src, dst, pbuf, z, xp, outacc, E, N);
    k_ln<<<N, 256, 0, stream>>>(outacc, x, bias, gamma, beta, out, N);
}

// Round 2
// 344.904 us; speedup vs baseline: 1.4813x; 1.4813x over previous
//
#include <hip/hip_runtime.h>

#define HID 256
#define NH 4
#define NEG 0.2f

__device__ __forceinline__ unsigned enc_f(float f) {
    unsigned u = __float_as_uint(f);
    return (u & 0x80000000u) ? ~u : (u | 0x80000000u);
}
__device__ __forceinline__ float dec_f(unsigned k) {
    return (k & 0x80000000u) ? __uint_as_float(k & 0x7FFFFFFFu)
                             : __uint_as_float(~k);
}

// ---- K0: wedot[h] = sum_c We[h*64+c] * att_edge[h*64+c] ----
__global__ void k_wedot(const float* __restrict__ We,
                        const float* __restrict__ att_edge,
                        float* __restrict__ wedot) {
    int t = threadIdx.x;
    float v = We[t] * att_edge[t];
    #pragma unroll
    for (int off = 32; off; off >>= 1) v += __shfl_down(v, off);
    if ((t & 63) == 0) wedot[t >> 6] = v;
}

// ---- K1: in-degree + incoming edge_attr sum ----
__global__ void k_deg(const int* __restrict__ dst,
                      const float* __restrict__ eattr,
                      float* __restrict__ deg, float* __restrict__ loopv,
                      int E) {
    int e = blockIdx.x * 256 + threadIdx.x;
    if (e >= E) return;
    int d = dst[e];
    atomicAdd(&deg[d], 1.0f);
    atomicAdd(&loopv[d], eattr[e]);
}

// ---- K2: xp = x @ W  (+ fused a_s, a_d head reductions) ----
__global__ __launch_bounds__(256) void k_gemm(
    const float* __restrict__ x, const float* __restrict__ W,
    const float* __restrict__ att_src, const float* __restrict__ att_dst,
    float* __restrict__ xp, float* __restrict__ a_s, float* __restrict__ a_d,
    int N) {
    __shared__ float xs[8][HID];
    int t = threadIdx.x;
    int n0 = blockIdx.x * 8;
    #pragma unroll
    for (int r = 0; r < 8; r++) {
        int n = n0 + r;
        xs[r][t] = (n < N) ? x[(size_t)n * HID + t] : 0.0f;
    }
    __syncthreads();
    float acc[8] = {0, 0, 0, 0, 0, 0, 0, 0};
    for (int k = 0; k < HID; k += 4) {
        float w0 = W[(size_t)(k + 0) * HID + t];
        float w1 = W[(size_t)(k + 1) * HID + t];
        float w2 = W[(size_t)(k + 2) * HID + t];
        float w3 = W[(size_t)(k + 3) * HID + t];
        #pragma unroll
        for (int r = 0; r < 8; r++) {
            float4 xv = *(const float4*)&xs[r][k];
            acc[r] += xv.x * w0 + xv.y * w1 + xv.z * w2 + xv.w * w3;
        }
    }
    float ws_ = att_src[t], wd_ = att_dst[t];
    int h = t >> 6;
    #pragma unroll
    for (int r = 0; r < 8; r++) {
        int n = n0 + r;
        float vs = acc[r] * ws_, vd = acc[r] * wd_;
        #pragma unroll
        for (int off = 32; off; off >>= 1) {
            vs += __shfl_down(vs, off);
            vd += __shfl_down(vd, off);
        }
        if (n < N) {
            xp[(size_t)n * HID + t] = acc[r];
            if ((t & 63) == 0) {
                a_s[n * NH + h] = vs;
                a_d[n * NH + h] = vd;
            }
        }
    }
}

// ---- K3: exclusive prefix scan of (deg+1) -> rowptr (single block) ----
__global__ __launch_bounds__(256) void k_scan(const float* __restrict__ deg,
                                              int* __restrict__ rowptr,
                                              int N) {
    __shared__ int wsum[4];
    __shared__ int carry_s;
    int t = threadIdx.x;
    int lane = t & 63;
    if (t == 0) carry_s = 0;
    __syncthreads();
    for (int base = 0; base < N; base += 256) {
        int i = base + t;
        int v = (i < N) ? ((int)(deg[i] + 0.5f) + 1) : 0;
        int incl = v;
        #pragma unroll
        for (int off = 1; off < 64; off <<= 1) {
            int up = __shfl_up(incl, off);
            if (lane >= off) incl += up;
        }
        if (lane == 63) wsum[t >> 6] = incl;
        __syncthreads();
        int woff = 0;
        for (int w = 0; w < (t >> 6); w++) woff += wsum[w];
        int carry = carry_s;
        if (i < N) rowptr[i] = carry + woff + incl - v;
        __syncthreads();
        if (t == 255) carry_s = carry + woff + incl;
        __syncthreads();
    }
    if (t == 0) rowptr[N] = carry_s;
}

// ---- K4: fill CSR adjacency (src, edge-id) per destination ----
__global__ void k_fill(const int* __restrict__ src, const int* __restrict__ dst,
                       const int* __restrict__ rowptr, int* __restrict__ cursor,
                       int2* __restrict__ adj, int E, int N) {
    int e = blockIdx.x * 256 + threadIdx.x;
    if (e >= E + N) return;
    int s, d;
    if (e < E) {
        s = src[e]; d = dst[e];
    } else {
        s = d = e - E;
    }
    int pos = atomicAdd(&cursor[d], 1);
    adj[rowptr[d] + pos] = make_int2(s, e);
}

// ---- K5: logits + leakyReLU + segment max (ordered-int atomicMax) ----
__global__ void k_logits(const int* __restrict__ src, const int* __restrict__ dst,
                         const float* __restrict__ eattr,
                         const float4* __restrict__ a_s4,
                         const float4* __restrict__ a_d4,
                         const float* __restrict__ wedot,
                         const float* __restrict__ deg,
                         const float* __restrict__ loopv,
                         float4* __restrict__ pbuf,
                         unsigned* __restrict__ mkey, int E, int N) {
    int e = blockIdx.x * 256 + threadIdx.x;
    if (e >= E + N) return;
    int s, d;
    float ea;
    if (e < E) {
        s = src[e]; d = dst[e]; ea = eattr[e];
    } else {
        s = d = e - E;
        ea = loopv[d] / fmaxf(deg[d], 1.0f);
    }
    float4 as = a_s4[s], ad = a_d4[d];
    float4 lg;
    lg.x = as.x + ad.x + ea * wedot[0];
    lg.y = as.y + ad.y + ea * wedot[1];
    lg.z = as.z + ad.z + ea * wedot[2];
    lg.w = as.w + ad.w + ea * wedot[3];
    lg.x = lg.x > 0.f ? lg.x : NEG * lg.x;
    lg.y = lg.y > 0.f ? lg.y : NEG * lg.y;
    lg.z = lg.z > 0.f ? lg.z : NEG * lg.z;
    lg.w = lg.w > 0.f ? lg.w : NEG * lg.w;
    pbuf[e] = lg;
    atomicMax(&mkey[d * 4 + 0], enc_f(lg.x));
    atomicMax(&mkey[d * 4 + 1], enc_f(lg.y));
    atomicMax(&mkey[d * 4 + 2], enc_f(lg.z));
    atomicMax(&mkey[d * 4 + 3], enc_f(lg.w));
}

// ---- K6: p = exp(logit - m[dst]); z = segment_sum(p) ----
__global__ void k_pz(const int* __restrict__ dst, float4* __restrict__ pbuf,
                     const unsigned* __restrict__ mkey, float* __restrict__ z,
                     int E, int N) {
    int e = blockIdx.x * 256 + threadIdx.x;
    if (e >= E + N) return;
    int d = (e < E) ? dst[e] : e - E;
    float4 lg = pbuf[e];
    float4 p;
    p.x = __expf(lg.x - dec_f(mkey[d * 4 + 0]));
    p.y = __expf(lg.y - dec_f(mkey[d * 4 + 1]));
    p.z = __expf(lg.z - dec_f(mkey[d * 4 + 2]));
    p.w = __expf(lg.w - dec_f(mkey[d * 4 + 3]));
    pbuf[e] = p;
    atomicAdd(&z[d * 4 + 0], p.x);
    atomicAdd(&z[d * 4 + 1], p.y);
    atomicAdd(&z[d * 4 + 2], p.z);
    atomicAdd(&z[d * 4 + 3], p.w);
}

// ---- K7: CSR gather + bias + LayerNorm + residual + ReLU (fused) ----
__global__ __launch_bounds__(256) void k_gather_ln(
    const int2* __restrict__ adj, const int* __restrict__ rowptr,
    const float* __restrict__ pbuf, const float* __restrict__ z,
    const float* __restrict__ xp, const float* __restrict__ x,
    const float* __restrict__ bias, const float* __restrict__ gamma,
    const float* __restrict__ beta, float* __restrict__ out, int N) {
    int n = blockIdx.x;
    int t = threadIdx.x;
    int h = t >> 6;
    int beg = rowptr[n], end = rowptr[n + 1];
    float zi = 1.0f / (z[n * 4 + h] + 1e-16f);
    float acc = 0.f;
    int j = beg;
    for (; j + 2 <= end; j += 2) {
        int2 a0 = adj[j];
        int2 a1 = adj[j + 1];
        float al0 = pbuf[(size_t)a0.y * 4 + h] * zi;
        float al1 = pbuf[(size_t)a1.y * 4 + h] * zi;
        float v0 = xp[(size_t)a0.x * HID + t];
        float v1 = xp[(size_t)a1.x * HID + t];
        acc += al0 * v0 + al1 * v1;
    }
    if (j < end) {
        int2 a0 = adj[j];
        acc += pbuf[(size_t)a0.y * 4 + h] * zi * xp[(size_t)a0.x * HID + t];
    }
    float v = acc + bias[t];
    float a = v, b = v * v;
    #pragma unroll
    for (int off = 32; off; off >>= 1) {
        a += __shfl_down(a, off);
        b += __shfl_down(b, off);
    }
    __shared__ float s1[4], s2[4];
    if ((t & 63) == 0) {
        s1[t >> 6] = a;
        s2[t >> 6] = b;
    }
    __syncthreads();
    float sum = s1[0] + s1[1] + s1[2] + s1[3];
    float sq = s2[0] + s2[1] + s2[2] + s2[3];
    float mu = sum * (1.0f / HID);
    float var = sq * (1.0f / HID) - mu * mu;
    float hn = (v - mu) * rsqrtf(var + 1e-5f) * gamma[t] + beta[t];
    float o = hn + x[(size_t)n * HID + t];
    out[(size_t)n * HID + t] = o > 0.f ? o : 0.f;
}

extern "C" void kernel_launch(void* const* d_in, const int* in_sizes, int n_in,
                              void* d_out, int out_size, void* d_ws,
                              size_t ws_size, hipStream_t stream) {
    const float* x        = (const float*)d_in[0];
    const int*   ei       = (const int*)d_in[1];
    const float* eattr    = (const float*)d_in[2];
    const float* W        = (const float*)d_in[3];
    const float* att_src  = (const float*)d_in[4];
    const float* att_dst  = (const float*)d_in[5];
    const float* We       = (const float*)d_in[6];
    const float* att_edge = (const float*)d_in[7];
    const float* bias     = (const float*)d_in[8];
    const float* gamma    = (const float*)d_in[9];
    const float* beta     = (const float*)d_in[10];

    int N = in_sizes[0] / HID;
    int E = in_sizes[1] / 2;
    const int* src = ei;
    const int* dst = ei + E;
    float* out = (float*)d_out;

    // workspace layout (floats)
    float* ws    = (float*)d_ws;
    float* xp    = ws;                          // N*HID
    float* pbuf  = xp + (size_t)N * HID;        // (E+N)*4
    float* a_s   = pbuf + (size_t)(E + N) * 4;  // N*4
    float* a_d   = a_s + (size_t)N * 4;         // N*4
    float* wedot = a_d + (size_t)N * 4;         // 4
    // ---- zeroed region start ----
    float* deg   = wedot + 4;                   // N
    float* loopv = deg + N;                     // N
    unsigned* mkey = (unsigned*)(loopv + N);    // N*4
    float* z     = (float*)(mkey + (size_t)N * 4);  // N*4
    int* cursor  = (int*)(z + (size_t)N * 4);   // N
    // ---- zeroed region end (11*N words) ----
    int* rowptr  = cursor + N;                  // N+2 (pad for int2 align)
    int2* adj    = (int2*)(rowptr + N + 2);     // (E+N)

    hipMemsetAsync(deg, 0, (size_t)11 * N * sizeof(float), stream);

    k_wedot<<<1, 256, 0, stream>>>(We, att_edge, wedot);
    k_deg<<<(E + 255) / 256, 256, 0, stream>>>(dst, eattr, deg, loopv, E);
    k_gemm<<<(N + 7) / 8, 256, 0, stream>>>(x, W, att_src, att_dst, xp, a_s,
                                            a_d, N);
    k_scan<<<1, 256, 0, stream>>>(deg, rowptr, N);
    int T = E + N;
    k_fill<<<(T + 255) / 256, 256, 0, stream>>>(src, dst, rowptr, cursor, adj,
                                                E, N);
    k_logits<<<(T + 255) / 256, 256, 0, stream>>>(
        src, dst, eattr, (const float4*)a_s, (const float4*)a_d, wedot, deg,
        loopv, (float4*)pbuf, mkey, E, N);
    k_pz<<<(T + 255) / 256, 256, 0, stream>>>(dst, (float4*)pbuf, mkey, z, E,
                                              N);
    k_gather_ln<<<N, 256, 0, stream>>>(adj, rowptr, pbuf, z, xp, x, bias,
                                       gamma, beta, out, N);
}

// Round 3
// 216.333 us; speedup vs baseline: 2.3616x; 1.5943x over previous
//
#include <hip/hip_runtime.h>

#define HID 256
#define NH 4
#define NEG 0.2f

// ---- K0: wedot[h] = sum_c We[h*64+c] * att_edge[h*64+c] ----
__global__ void k_wedot(const float* __restrict__ We,
                        const float* __restrict__ att_edge,
                        float* __restrict__ wedot) {
    int t = threadIdx.x;
    float v = We[t] * att_edge[t];
    #pragma unroll
    for (int off = 32; off; off >>= 1) v += __shfl_down(v, off);
    if ((t & 63) == 0) wedot[t >> 6] = v;
}

// ---- K1: in-degree + incoming edge_attr sum ----
__global__ void k_deg(const int* __restrict__ dst,
                      const float* __restrict__ eattr,
                      float* __restrict__ deg, float* __restrict__ loopv,
                      int E) {
    int e = blockIdx.x * 256 + threadIdx.x;
    if (e >= E) return;
    int d = dst[e];
    atomicAdd(&deg[d], 1.0f);
    atomicAdd(&loopv[d], eattr[e]);
}

// ---- K2: xp = x @ W  (+ fused a_s, a_d head reductions) ----
__global__ __launch_bounds__(256) void k_gemm(
    const float* __restrict__ x, const float* __restrict__ W,
    const float* __restrict__ att_src, const float* __restrict__ att_dst,
    float* __restrict__ xp, float* __restrict__ a_s, float* __restrict__ a_d,
    int N) {
    __shared__ float xs[8][HID];
    int t = threadIdx.x;
    int n0 = blockIdx.x * 8;
    #pragma unroll
    for (int r = 0; r < 8; r++) {
        int n = n0 + r;
        xs[r][t] = (n < N) ? x[(size_t)n * HID + t] : 0.0f;
    }
    __syncthreads();
    float acc[8] = {0, 0, 0, 0, 0, 0, 0, 0};
    for (int k = 0; k < HID; k += 4) {
        float w0 = W[(size_t)(k + 0) * HID + t];
        float w1 = W[(size_t)(k + 1) * HID + t];
        float w2 = W[(size_t)(k + 2) * HID + t];
        float w3 = W[(size_t)(k + 3) * HID + t];
        #pragma unroll
        for (int r = 0; r < 8; r++) {
            float4 xv = *(const float4*)&xs[r][k];
            acc[r] += xv.x * w0 + xv.y * w1 + xv.z * w2 + xv.w * w3;
        }
    }
    float ws_ = att_src[t], wd_ = att_dst[t];
    int h = t >> 6;
    #pragma unroll
    for (int r = 0; r < 8; r++) {
        int n = n0 + r;
        float vs = acc[r] * ws_, vd = acc[r] * wd_;
        #pragma unroll
        for (int off = 32; off; off >>= 1) {
            vs += __shfl_down(vs, off);
            vd += __shfl_down(vd, off);
        }
        if (n < N) {
            xp[(size_t)n * HID + t] = acc[r];
            if ((t & 63) == 0) {
                a_s[n * NH + h] = vs;
                a_d[n * NH + h] = vd;
            }
        }
    }
}

// ---- K3: exclusive prefix scan of (deg+1) -> rowptr (single block) ----
__global__ __launch_bounds__(256) void k_scan(const float* __restrict__ deg,
                                              int* __restrict__ rowptr,
                                              int N) {
    __shared__ int wsum[4];
    __shared__ int carry_s;
    int t = threadIdx.x;
    int lane = t & 63;
    if (t == 0) carry_s = 0;
    __syncthreads();
    for (int base = 0; base < N; base += 256) {
        int i = base + t;
        int v = (i < N) ? ((int)(deg[i] + 0.5f) + 1) : 0;
        int incl = v;
        #pragma unroll
        for (int off = 1; off < 64; off <<= 1) {
            int up = __shfl_up(incl, off);
            if (lane >= off) incl += up;
        }
        if (lane == 63) wsum[t >> 6] = incl;
        __syncthreads();
        int woff = 0;
        for (int w = 0; w < (t >> 6); w++) woff += wsum[w];
        int carry = carry_s;
        if (i < N) rowptr[i] = carry + woff + incl - v;
        __syncthreads();
        if (t == 255) carry_s = carry + woff + incl;
        __syncthreads();
    }
    if (t == 0) rowptr[N] = carry_s;
}

// ---- K4: fill CSR adjacency (src, edge-id) per destination ----
__global__ void k_fill(const int* __restrict__ src, const int* __restrict__ dst,
                       const int* __restrict__ rowptr, int* __restrict__ cursor,
                       int2* __restrict__ adj, int E, int N) {
    int e = blockIdx.x * 256 + threadIdx.x;
    if (e >= E + N) return;
    int s, d;
    if (e < E) {
        s = src[e]; d = dst[e];
    } else {
        s = d = e - E;
    }
    int pos = atomicAdd(&cursor[d], 1);
    adj[rowptr[d] + pos] = make_int2(s, e);
}

// ---- K5: fused online-softmax CSR gather + bias + LN + residual + ReLU ----
__global__ __launch_bounds__(256) void k_gather_ln(
    const int2* __restrict__ adj, const int* __restrict__ rowptr,
    const float* __restrict__ a_s, const float* __restrict__ a_d,
    const float* __restrict__ eattr, const float* __restrict__ wedot,
    const float* __restrict__ deg, const float* __restrict__ loopv,
    const float* __restrict__ xp, const float* __restrict__ x,
    const float* __restrict__ bias, const float* __restrict__ gamma,
    const float* __restrict__ beta, float* __restrict__ out, int E, int N) {
    __shared__ float sp[NH][64];
    __shared__ int ssrc[64];
    int n = blockIdx.x;
    int t = threadIdx.x;
    int h = t >> 6;        // wave == head
    int lane = t & 63;
    int beg = rowptr[n];
    int cnt = rowptr[n + 1] - beg;
    float adn = a_d[n * NH + h];
    float wh = wedot[h];
    float loop_ea = loopv[n] / fmaxf(deg[n], 1.0f);

    float m = -1e30f, z = 0.f, acc = 0.f;
    int ntile = (cnt + 63) >> 6;
    for (int tile = 0; tile < ntile; tile++) {
        int j = (tile << 6) + lane;
        float lg = -1e30f;
        int s = 0;
        if (j < cnt) {
            int2 a = adj[beg + j];
            s = a.x;
            float ea = (a.y < E) ? eattr[a.y] : loop_ea;
            lg = a_s[s * NH + h] + adn + ea * wh;
            lg = lg > 0.f ? lg : NEG * lg;
        }
        // wave-wide max of this tile
        float cm = lg;
        #pragma unroll
        for (int off = 32; off; off >>= 1) cm = fmaxf(cm, __shfl_xor(cm, off));
        float mn = fmaxf(m, cm);
        float scale = __expf(m - mn);
        float p = __expf(lg - mn);     // 0 for inactive lanes
        m = mn;
        acc *= scale;
        z *= scale;
        // wave-wide sum of p
        float zt = p;
        #pragma unroll
        for (int off = 32; off; off >>= 1) zt += __shfl_xor(zt, off);
        z += zt;
        sp[h][lane] = p;
        if (h == 0) ssrc[lane] = s;
        __syncthreads();
        int lim = min(64, cnt - (tile << 6));
        for (int jj = 0; jj < lim; jj++) {
            acc += sp[h][jj] * xp[(size_t)ssrc[jj] * HID + t];
        }
        __syncthreads();
    }

    float v = acc / (z + 1e-16f) + bias[t];
    float a = v, b = v * v;
    #pragma unroll
    for (int off = 32; off; off >>= 1) {
        a += __shfl_down(a, off);
        b += __shfl_down(b, off);
    }
    __shared__ float s1[4], s2[4];
    if ((t & 63) == 0) {
        s1[t >> 6] = a;
        s2[t >> 6] = b;
    }
    __syncthreads();
    float sum = s1[0] + s1[1] + s1[2] + s1[3];
    float sq = s2[0] + s2[1] + s2[2] + s2[3];
    float mu = sum * (1.0f / HID);
    float var = sq * (1.0f / HID) - mu * mu;
    float hn = (v - mu) * rsqrtf(var + 1e-5f) * gamma[t] + beta[t];
    float o = hn + x[(size_t)n * HID + t];
    out[(size_t)n * HID + t] = o > 0.f ? o : 0.f;
}

extern "C" void kernel_launch(void* const* d_in, const int* in_sizes, int n_in,
                              void* d_out, int out_size, void* d_ws,
                              size_t ws_size, hipStream_t stream) {
    const float* x        = (const float*)d_in[0];
    const int*   ei       = (const int*)d_in[1];
    const float* eattr    = (const float*)d_in[2];
    const float* W        = (const float*)d_in[3];
    const float* att_src  = (const float*)d_in[4];
    const float* att_dst  = (const float*)d_in[5];
    const float* We       = (const float*)d_in[6];
    const float* att_edge = (const float*)d_in[7];
    const float* bias     = (const float*)d_in[8];
    const float* gamma    = (const float*)d_in[9];
    const float* beta     = (const float*)d_in[10];

    int N = in_sizes[0] / HID;
    int E = in_sizes[1] / 2;
    const int* src = ei;
    const int* dst = ei + E;
    float* out = (float*)d_out;

    // workspace layout (floats)
    float* ws    = (float*)d_ws;
    float* xp    = ws;                          // N*HID
    float* a_s   = xp + (size_t)N * HID;        // N*4
    float* a_d   = a_s + (size_t)N * 4;         // N*4
    float* wedot = a_d + (size_t)N * 4;         // 4
    // ---- zeroed region start ----
    float* deg   = wedot + 4;                   // N
    float* loopv = deg + N;                     // N
    int* cursor  = (int*)(loopv + N);           // N
    // ---- zeroed region end (3*N words) ----
    int* rowptr  = cursor + N;                  // N+2 (pad for int2 align)
    int2* adj    = (int2*)(rowptr + N + 2);     // (E+N)

    hipMemsetAsync(deg, 0, (size_t)3 * N * sizeof(float), stream);

    k_wedot<<<1, 256, 0, stream>>>(We, att_edge, wedot);
    k_deg<<<(E + 255) / 256, 256, 0, stream>>>(dst, eattr, deg, loopv, E);
    k_gemm<<<(N + 7) / 8, 256, 0, stream>>>(x, W, att_src, att_dst, xp, a_s,
                                            a_d, N);
    k_scan<<<1, 256, 0, stream>>>(deg, rowptr, N);
    int T = E + N;
    k_fill<<<(T + 255) / 256, 256, 0, stream>>>(src, dst, rowptr, cursor, adj,
                                                E, N);
    k_gather_ln<<<N, 256, 0, stream>>>(adj, rowptr, a_s, a_d, eattr, wedot,
                                       deg, loopv, xp, x, bias, gamma, beta,
                                       out, E, N);
}

// Round 4
// 162.210 us; speedup vs baseline: 3.1496x; 1.3337x over previous
//
#include <hip/hip_runtime.h>

#define HID 256
#define NH 4
#define NEG 0.2f

typedef __attribute__((ext_vector_type(8))) short short8;
typedef __attribute__((ext_vector_type(4))) float f32x4;

__device__ __forceinline__ unsigned short f2b(float f) {
    unsigned u = __float_as_uint(f);
    u = u + 0x7FFFu + ((u >> 16) & 1u);
    return (unsigned short)(u >> 16);
}
__device__ __forceinline__ float b2f(unsigned short v) {
    return __uint_as_float(((unsigned)v) << 16);
}

// ---- K_prep: fused  [x->Ap bf16 frag-pack | W->Bp bf16 frag-pack | wedot |
//                      degree/loop-attr atomics]  ----
// A frag layout: elem((fi,ks,lane,j)) = A[fi*16+(lane&15)][ks*32+(lane>>4)*8+j]
// B frag layout: elem((ni,ks,lane,j)) = B[ks*32+(lane>>4)*8+j][ni*16+(lane&15)]
__global__ __launch_bounds__(256) void k_prep(
    const float* __restrict__ x, const float* __restrict__ W,
    const float* __restrict__ We, const float* __restrict__ att_edge,
    const int* __restrict__ dst, const float* __restrict__ eattr,
    unsigned short* __restrict__ Ap, unsigned short* __restrict__ Bp,
    float* __restrict__ wedot, int* __restrict__ deg,
    float* __restrict__ loopv, int N, int E, int XB) {
    int b = blockIdx.x, t = threadIdx.x;
    if (b < XB) {  // ---- pack x (N*64 float4 units) ----
        int i = b * 256 + t;
        if (i < N * 64) {
            int row = i >> 6, c4 = i & 63;
            float4 v = ((const float4*)x)[i];
            int k0 = c4 << 2;
            int ks = k0 >> 5, ko = k0 & 31;
            int lane = (row & 15) + ((ko >> 3) << 4);
            int fi = row >> 4;
            size_t base = ((size_t)(fi * 8 + ks) * 64 + lane) * 8 + (ko & 7);
            unsigned u0 = (unsigned)f2b(v.x) | ((unsigned)f2b(v.y) << 16);
            unsigned u1 = (unsigned)f2b(v.z) | ((unsigned)f2b(v.w) << 16);
            *(uint2*)(Ap + base) = make_uint2(u0, u1);
        }
    } else if (b < XB + 64) {  // ---- pack W (16384 float4 units) ----
        int i = (b - XB) * 256 + t;
        int k = i >> 6, c4 = i & 63;
        float4 v = ((const float4*)W)[i];
        float vv[4] = {v.x, v.y, v.z, v.w};
        int ks = k >> 5;
        int lhi = ((k & 31) >> 3) << 4;
        int j = k & 7;
        #pragma unroll
        for (int u = 0; u < 4; u++) {
            int n = (c4 << 2) + u;
            size_t e = ((size_t)((n >> 4) * 8 + ks) * 64 + lhi + (n & 15)) * 8 + j;
            Bp[e] = f2b(vv[u]);
        }
    } else if (b == XB + 64) {  // ---- wedot ----
        float v = We[t] * att_edge[t];
        #pragma unroll
        for (int off = 32; off; off >>= 1) v += __shfl_down(v, off);
        if ((t & 63) == 0) wedot[t >> 6] = v;
    } else {  // ---- degree + loop attr ----
        int e = (b - XB - 65) * 256 + t;
        if (e < E) {
            int d = dst[e];
            atomicAdd(&deg[d], 1);
            atomicAdd(&loopv[d], eattr[e]);
        }
    }
}

// ---- K_scan: exclusive prefix scan of (deg+1) -> rowptr, 1024 thr ----
__global__ __launch_bounds__(1024) void k_scan(const int* __restrict__ deg,
                                               int* __restrict__ rowptr,
                                               int N) {
    __shared__ int wsum[16], woff[16];
    int t = threadIdx.x, lane = t & 63, w = t >> 6;
    int base = t * 10;
    int d[10], s = 0;
    #pragma unroll
    for (int u = 0; u < 10; u++) {
        int i = base + u;
        int v = (i < N) ? (deg[i] + 1) : 0;
        d[u] = v;
        s += v;
    }
    int incl = s;
    #pragma unroll
    for (int off = 1; off < 64; off <<= 1) {
        int up = __shfl_up(incl, off);
        if (lane >= off) incl += up;
    }
    if (lane == 63) wsum[w] = incl;
    __syncthreads();
    if (t < 16) {
        int v = wsum[t];
        int inc = v;
        #pragma unroll
        for (int off = 1; off < 16; off <<= 1) {
            int up = __shfl_up(inc, off);
            if (t >= off) inc += up;
        }
        woff[t] = inc - v;
    }
    __syncthreads();
    int run = woff[w] + (incl - s);
    #pragma unroll
    for (int u = 0; u < 10; u++) {
        int i = base + u;
        if (i < N) {
            rowptr[i] = run;
            run += d[u];
        }
    }
    if (base < N && base + 10 >= N) rowptr[N] = run;
}

// ---- K_fill: CSR adjacency; adj = (src, eattr-value bits) ----
__global__ void k_fill(const int* __restrict__ src, const int* __restrict__ dst,
                       const float* __restrict__ eattr,
                       const int* __restrict__ deg,
                       const float* __restrict__ loopv,
                       const int* __restrict__ rowptr, int* __restrict__ cursor,
                       int2* __restrict__ adj, int E, int N) {
    int e = blockIdx.x * 256 + threadIdx.x;
    if (e >= E + N) return;
    int s, d;
    float ea;
    if (e < E) {
        s = src[e]; d = dst[e]; ea = eattr[e];
    } else {
        s = d = e - E;
        ea = loopv[d] / fmaxf((float)deg[d], 1.0f);
    }
    int pos = atomicAdd(&cursor[d], 1);
    adj[rowptr[d] + pos] = make_int2(s, __float_as_int(ea));
}

// ---- K_mfma: xp = x@W via bf16 MFMA, fused a_s/a_d epilogue ----
// block = 4 waves; wave w = 64-col strip (== head w); block = 64 rows
__global__ __launch_bounds__(256) void k_mfma(
    const unsigned short* __restrict__ Ap, const unsigned short* __restrict__ Bp,
    const float* __restrict__ att_src, const float* __restrict__ att_dst,
    unsigned short* __restrict__ xp, float* __restrict__ a_s,
    float* __restrict__ a_d, int N, int MF) {
    int t = threadIdx.x, w = t >> 6, l = t & 63;
    int fi0 = blockIdx.x * 4;
    const short8* A8 = (const short8*)Ap;
    const short8* B8 = (const short8*)Bp;
    f32x4 acc[4][4];
    #pragma unroll
    for (int mi = 0; mi < 4; mi++)
        #pragma unroll
        for (int ni = 0; ni < 4; ni++)
            acc[mi][ni] = (f32x4){0.f, 0.f, 0.f, 0.f};
    short8 zz = {0, 0, 0, 0, 0, 0, 0, 0};
    #pragma unroll
    for (int ks = 0; ks < 8; ks++) {
        short8 a[4], b[4];
        #pragma unroll
        for (int mi = 0; mi < 4; mi++) {
            int fi = fi0 + mi;
            a[mi] = (fi < MF) ? A8[(size_t)(fi * 8 + ks) * 64 + l] : zz;
        }
        #pragma unroll
        for (int ni = 0; ni < 4; ni++)
            b[ni] = B8[(size_t)(((w << 2) + ni) * 8 + ks) * 64 + l];
        #pragma unroll
        for (int mi = 0; mi < 4; mi++)
            #pragma unroll
            for (int ni = 0; ni < 4; ni++)
                acc[mi][ni] = __builtin_amdgcn_mfma_f32_16x16x32_bf16(
                    a[mi], b[ni], acc[mi][ni], 0, 0, 0);
    }
    // epilogue: store xp bf16; fused a_s/a_d head reductions
    int colb = w << 6;
    float asc[4], adc[4];
    #pragma unroll
    for (int ni = 0; ni < 4; ni++) {
        asc[ni] = att_src[colb + ni * 16 + (l & 15)];
        adc[ni] = att_dst[colb + ni * 16 + (l & 15)];
    }
    #pragma unroll
    for (int mi = 0; mi < 4; mi++) {
        int rowb = fi0 * 16 + mi * 16 + ((l >> 4) << 2);
        #pragma unroll
        for (int r = 0; r < 4; r++) {
            int row = rowb + r;
            float ps = 0.f, pd = 0.f;
            #pragma unroll
            for (int ni = 0; ni < 4; ni++) {
                float v = acc[mi][ni][r];
                ps += v * asc[ni];
                pd += v * adc[ni];
            }
            #pragma unroll
            for (int off = 1; off < 16; off <<= 1) {
                ps += __shfl_xor(ps, off);
                pd += __shfl_xor(pd, off);
            }
            if (row < N) {
                if ((l & 15) == 0) {
                    a_s[(row << 2) + w] = ps;
                    a_d[(row << 2) + w] = pd;
                }
                #pragma unroll
                for (int ni = 0; ni < 4; ni++)
                    xp[(size_t)row * HID + colb + ni * 16 + (l & 15)] =
                        f2b(acc[mi][ni][r]);
            }
        }
    }
}

// ---- K_gather_ln: fused online-softmax CSR gather + bias+LN+res+ReLU ----
__global__ __launch_bounds__(256) void k_gather_ln(
    const int2* __restrict__ adj, const int* __restrict__ rowptr,
    const float* __restrict__ a_s, const float* __restrict__ a_d,
    const float* __restrict__ wedot, const unsigned short* __restrict__ xp,
    const float* __restrict__ x, const float* __restrict__ bias,
    const float* __restrict__ gamma, const float* __restrict__ beta,
    float* __restrict__ out, int N) {
    __shared__ float sp[NH][64];
    __shared__ int ssrc[64];
    int n = blockIdx.x;
    int t = threadIdx.x;
    int h = t >> 6;
    int lane = t & 63;
    int beg = rowptr[n];
    int cnt = rowptr[n + 1] - beg;
    float adn = a_d[n * NH + h];
    float wh = wedot[h];

    float m = -1e30f, z = 0.f, acc = 0.f;
    int ntile = (cnt + 63) >> 6;
    for (int tile = 0; tile < ntile; tile++) {
        int j = (tile << 6) + lane;
        float lg = -1e30f;
        int s = 0;
        if (j < cnt) {
            int2 a = adj[beg + j];
            s = a.x;
            float ea = __int_as_float(a.y);
            lg = a_s[s * NH + h] + adn + ea * wh;
            lg = lg > 0.f ? lg : NEG * lg;
        }
        float cm = lg;
        #pragma unroll
        for (int off = 32; off; off >>= 1) cm = fmaxf(cm, __shfl_xor(cm, off));
        float mn = fmaxf(m, cm);
        float scale = __expf(m - mn);
        float p = __expf(lg - mn);
        m = mn;
        acc *= scale;
        z *= scale;
        float zt = p;
        #pragma unroll
        for (int off = 32; off; off >>= 1) zt += __shfl_xor(zt, off);
        z += zt;
        sp[h][lane] = p;
        if (h == 0) ssrc[lane] = s;
        __syncthreads();
        int lim = min(64, cnt - (tile << 6));
        int jj = 0;
        for (; jj + 2 <= lim; jj += 2) {
            float p0 = sp[h][jj], p1 = sp[h][jj + 1];
            unsigned short v0 = xp[(size_t)ssrc[jj] * HID + t];
            unsigned short v1 = xp[(size_t)ssrc[jj + 1] * HID + t];
            acc += p0 * b2f(v0) + p1 * b2f(v1);
        }
        if (jj < lim) acc += sp[h][jj] * b2f(xp[(size_t)ssrc[jj] * HID + t]);
        __syncthreads();
    }

    float v = acc / (z + 1e-16f) + bias[t];
    float a = v, b = v * v;
    #pragma unroll
    for (int off = 32; off; off >>= 1) {
        a += __shfl_down(a, off);
        b += __shfl_down(b, off);
    }
    __shared__ float s1[4], s2[4];
    if ((t & 63) == 0) {
        s1[t >> 6] = a;
        s2[t >> 6] = b;
    }
    __syncthreads();
    float sum = s1[0] + s1[1] + s1[2] + s1[3];
    float sq = s2[0] + s2[1] + s2[2] + s2[3];
    float mu = sum * (1.0f / HID);
    float var = sq * (1.0f / HID) - mu * mu;
    float hn = (v - mu) * rsqrtf(var + 1e-5f) * gamma[t] + beta[t];
    float o = hn + x[(size_t)n * HID + t];
    out[(size_t)n * HID + t] = o > 0.f ? o : 0.f;
}

extern "C" void kernel_launch(void* const* d_in, const int* in_sizes, int n_in,
                              void* d_out, int out_size, void* d_ws,
                              size_t ws_size, hipStream_t stream) {
    const float* x        = (const float*)d_in[0];
    const int*   ei       = (const int*)d_in[1];
    const float* eattr    = (const float*)d_in[2];
    const float* W        = (const float*)d_in[3];
    const float* att_src  = (const float*)d_in[4];
    const float* att_dst  = (const float*)d_in[5];
    const float* We       = (const float*)d_in[6];
    const float* att_edge = (const float*)d_in[7];
    const float* bias     = (const float*)d_in[8];
    const float* gamma    = (const float*)d_in[9];
    const float* beta     = (const float*)d_in[10];

    int N = in_sizes[0] / HID;
    int E = in_sizes[1] / 2;
    const int* src = ei;
    const int* dst = ei + E;
    float* out = (float*)d_out;

    // workspace layout (32-bit words)
    float* base = (float*)d_ws;
    unsigned short* Ap = (unsigned short*)base;            // N*128 words
    unsigned short* Bp = (unsigned short*)(base + (size_t)N * 128);  // 32768 w
    unsigned short* xp = (unsigned short*)(base + (size_t)N * 128 + 32768);
    float* a_s   = base + (size_t)N * 256 + 32768;         // N*4
    float* a_d   = a_s + (size_t)N * 4;                    // N*4
    float* wedot = a_d + (size_t)N * 4;                    // 4
    // ---- zeroed region ----
    int* deg     = (int*)(wedot + 4);                      // N
    float* loopv = (float*)(deg + N);                      // N
    int* cursor  = (int*)(loopv + N);                      // N
    // ---- end zeroed ----
    int* rowptr  = cursor + N;                             // N+2
    int2* adj    = (int2*)(rowptr + N + 2);                // E+N

    hipMemsetAsync(deg, 0, (size_t)3 * N * sizeof(int), stream);

    int XB = (N * 64 + 255) / 256;
    int DB = (E + 255) / 256;
    k_prep<<<XB + 65 + DB, 256, 0, stream>>>(x, W, We, att_edge, dst, eattr,
                                             Ap, Bp, wedot, deg, loopv, N, E,
                                             XB);
    k_scan<<<1, 1024, 0, stream>>>(deg, rowptr, N);
    int T = E + N;
    k_fill<<<(T + 255) / 256, 256, 0, stream>>>(src, dst, eattr, deg, loopv,
                                                rowptr, cursor, adj, E, N);
    int MF = (N + 15) / 16;
    k_mfma<<<(MF + 3) / 4, 256, 0, stream>>>(Ap, Bp, att_src, att_dst, xp, a_s,
                                             a_d, N, MF);
    k_gather_ln<<<N, 256, 0, stream>>>(adj, rowptr, a_s, a_d, wedot, xp, x,
                                       bias, gamma, beta, out, N);
}

// Round 5
// 107.528 us; speedup vs baseline: 4.7513x; 1.5085x over previous
//
#include <hip/hip_runtime.h>

#define HID 256
#define NH 4
#define NEG 0.2f

typedef __attribute__((ext_vector_type(8))) short short8;
typedef __attribute__((ext_vector_type(4))) float f32x4;

__device__ __forceinline__ unsigned short f2b(float f) {
    unsigned u = __float_as_uint(f);
    u = u + 0x7FFFu + ((u >> 16) & 1u);
    return (unsigned short)(u >> 16);
}
__device__ __forceinline__ float b2f_lo(unsigned u) {
    return __uint_as_float(u << 16);
}
__device__ __forceinline__ float b2f_hi(unsigned u) {
    return __uint_as_float(u & 0xFFFF0000u);
}
__device__ __forceinline__ float lrelu(float f) {
    return f > 0.f ? f : NEG * f;
}

// ---- K_prep: fused [x->Ap pack | W->Bp pack | wedot | deg/pos/loopv] ----
__global__ __launch_bounds__(256) void k_prep(
    const float* __restrict__ x, const float* __restrict__ W,
    const float* __restrict__ We, const float* __restrict__ att_edge,
    const int* __restrict__ dst, const float* __restrict__ eattr,
    unsigned short* __restrict__ Ap, unsigned short* __restrict__ Bp,
    float* __restrict__ wedot, int* __restrict__ deg, int* __restrict__ pos,
    float* __restrict__ loopv, int N, int E, int XB) {
    int b = blockIdx.x, t = threadIdx.x;
    if (b < XB) {  // ---- pack x (N*64 float4 units) ----
        int i = b * 256 + t;
        if (i < N * 64) {
            int row = i >> 6, c4 = i & 63;
            float4 v = ((const float4*)x)[i];
            int k0 = c4 << 2;
            int ks = k0 >> 5, ko = k0 & 31;
            int lane = (row & 15) + ((ko >> 3) << 4);
            int fi = row >> 4;
            size_t base = ((size_t)(fi * 8 + ks) * 64 + lane) * 8 + (ko & 7);
            unsigned u0 = (unsigned)f2b(v.x) | ((unsigned)f2b(v.y) << 16);
            unsigned u1 = (unsigned)f2b(v.z) | ((unsigned)f2b(v.w) << 16);
            *(uint2*)(Ap + base) = make_uint2(u0, u1);
        }
    } else if (b < XB + 64) {  // ---- pack W ----
        int i = (b - XB) * 256 + t;
        int k = i >> 6, c4 = i & 63;
        float4 v = ((const float4*)W)[i];
        float vv[4] = {v.x, v.y, v.z, v.w};
        int ks = k >> 5;
        int lhi = ((k & 31) >> 3) << 4;
        int j = k & 7;
        #pragma unroll
        for (int u = 0; u < 4; u++) {
            int n = (c4 << 2) + u;
            size_t e = ((size_t)((n >> 4) * 8 + ks) * 64 + lhi + (n & 15)) * 8 + j;
            Bp[e] = f2b(vv[u]);
        }
    } else if (b == XB + 64) {  // ---- wedot ----
        float v = We[t] * att_edge[t];
        #pragma unroll
        for (int off = 32; off; off >>= 1) v += __shfl_down(v, off);
        if ((t & 63) == 0) wedot[t >> 6] = v;
    } else {  // ---- degree (capture slot) + loop attr ----
        int e = (b - XB - 65) * 256 + t;
        if (e < E) {
            int d = dst[e];
            pos[e] = atomicAdd(&deg[d], 1);
            atomicAdd(&loopv[d], eattr[e]);
        }
    }
}

// ---- K_scan: exclusive prefix scan of deg -> rowptr (real edges only) ----
__global__ __launch_bounds__(1024) void k_scan(const int* __restrict__ deg,
                                               int* __restrict__ rowptr,
                                               int N) {
    __shared__ int wsum[16], woff[16];
    int t = threadIdx.x, lane = t & 63, w = t >> 6;
    int base = t * 10;
    int d[10], s = 0;
    #pragma unroll
    for (int u = 0; u < 10; u++) {
        int i = base + u;
        int v = (i < N) ? deg[i] : 0;
        d[u] = v;
        s += v;
    }
    int incl = s;
    #pragma unroll
    for (int off = 1; off < 64; off <<= 1) {
        int up = __shfl_up(incl, off);
        if (lane >= off) incl += up;
    }
    if (lane == 63) wsum[w] = incl;
    __syncthreads();
    if (t < 16) {
        int v = wsum[t];
        int inc = v;
        #pragma unroll
        for (int off = 1; off < 16; off <<= 1) {
            int up = __shfl_up(inc, off);
            if (t >= off) inc += up;
        }
        woff[t] = inc - v;
    }
    __syncthreads();
    int run = woff[w] + (incl - s);
    #pragma unroll
    for (int u = 0; u < 10; u++) {
        int i = base + u;
        if (i < N) {
            rowptr[i] = run;
            run += d[u];
        }
    }
    if (base < N && base + 10 >= N) rowptr[N] = run;
}

// ---- K_fill: pure scatter write (no atomics) ----
__global__ void k_fill(const int* __restrict__ src, const int* __restrict__ dst,
                       const float* __restrict__ eattr,
                       const int* __restrict__ rowptr,
                       const int* __restrict__ pos, int2* __restrict__ adj,
                       int E) {
    int e = blockIdx.x * 256 + threadIdx.x;
    if (e >= E) return;
    adj[rowptr[dst[e]] + pos[e]] = make_int2(src[e], __float_as_int(eattr[e]));
}

// ---- K_mfma: xp = x@W via bf16 MFMA, fused a_s/a_d epilogue ----
__global__ __launch_bounds__(256) void k_mfma(
    const unsigned short* __restrict__ Ap, const unsigned short* __restrict__ Bp,
    const float* __restrict__ att_src, const float* __restrict__ att_dst,
    unsigned short* __restrict__ xp, float* __restrict__ a_s,
    float* __restrict__ a_d, int N, int MF) {
    int t = threadIdx.x, w = t >> 6, l = t & 63;
    int fi0 = blockIdx.x * 4;
    const short8* A8 = (const short8*)Ap;
    const short8* B8 = (const short8*)Bp;
    f32x4 acc[4][4];
    #pragma unroll
    for (int mi = 0; mi < 4; mi++)
        #pragma unroll
        for (int ni = 0; ni < 4; ni++)
            acc[mi][ni] = (f32x4){0.f, 0.f, 0.f, 0.f};
    short8 zz = {0, 0, 0, 0, 0, 0, 0, 0};
    #pragma unroll
    for (int ks = 0; ks < 8; ks++) {
        short8 a[4], b[4];
        #pragma unroll
        for (int mi = 0; mi < 4; mi++) {
            int fi = fi0 + mi;
            a[mi] = (fi < MF) ? A8[(size_t)(fi * 8 + ks) * 64 + l] : zz;
        }
        #pragma unroll
        for (int ni = 0; ni < 4; ni++)
            b[ni] = B8[(size_t)(((w << 2) + ni) * 8 + ks) * 64 + l];
        #pragma unroll
        for (int mi = 0; mi < 4; mi++)
            #pragma unroll
            for (int ni = 0; ni < 4; ni++)
                acc[mi][ni] = __builtin_amdgcn_mfma_f32_16x16x32_bf16(
                    a[mi], b[ni], acc[mi][ni], 0, 0, 0);
    }
    int colb = w << 6;
    float asc[4], adc[4];
    #pragma unroll
    for (int ni = 0; ni < 4; ni++) {
        asc[ni] = att_src[colb + ni * 16 + (l & 15)];
        adc[ni] = att_dst[colb + ni * 16 + (l & 15)];
    }
    #pragma unroll
    for (int mi = 0; mi < 4; mi++) {
        int rowb = fi0 * 16 + mi * 16 + ((l >> 4) << 2);
        #pragma unroll
        for (int r = 0; r < 4; r++) {
            int row = rowb + r;
            float ps = 0.f, pd = 0.f;
            #pragma unroll
            for (int ni = 0; ni < 4; ni++) {
                float v = acc[mi][ni][r];
                ps += v * asc[ni];
                pd += v * adc[ni];
            }
            #pragma unroll
            for (int off = 1; off < 16; off <<= 1) {
                ps += __shfl_xor(ps, off);
                pd += __shfl_xor(pd, off);
            }
            if (row < N) {
                if ((l & 15) == 0) {
                    a_s[(row << 2) + w] = ps;
                    a_d[(row << 2) + w] = pd;
                }
                #pragma unroll
                for (int ni = 0; ni < 4; ni++)
                    xp[(size_t)row * HID + colb + ni * 16 + (l & 15)] =
                        f2b(acc[mi][ni][r]);
            }
        }
    }
}

// ---- K_gather_ln: wave-per-node online-softmax gather + bias+LN+res+ReLU ----
__global__ __launch_bounds__(256) void k_gather_ln(
    const int2* __restrict__ adj, const int* __restrict__ rowptr,
    const float4* __restrict__ a_s4, const float4* __restrict__ a_d4,
    const float* __restrict__ wedot, const int* __restrict__ deg,
    const float* __restrict__ loopv, const unsigned short* __restrict__ xp,
    const float4* __restrict__ x4, const float4* __restrict__ bias4,
    const float4* __restrict__ gamma4, const float4* __restrict__ beta4,
    float4* __restrict__ out4, int N) {
    __shared__ float4 sp[4][64];
    __shared__ int ssrc[4][64];
    int t = threadIdx.x;
    int u = t >> 6, l = t & 63, hl = l >> 4;
    int n = blockIdx.x * 4 + u;
    if (n >= N) return;
    int beg = rowptr[n], cnt = rowptr[n + 1] - beg;
    float4 adn = a_d4[n];
    float4 wh = *(const float4*)wedot;
    float loop_ea = loopv[n] / fmaxf((float)deg[n], 1.0f);
    float4 asn = a_s4[n];
    // self-loop initializes the online softmax: p_self = 1
    float4 m4;
    m4.x = lrelu(asn.x + adn.x + loop_ea * wh.x);
    m4.y = lrelu(asn.y + adn.y + loop_ea * wh.y);
    m4.z = lrelu(asn.z + adn.z + loop_ea * wh.z);
    m4.w = lrelu(asn.w + adn.w + loop_ea * wh.w);
    float4 z4 = {1.f, 1.f, 1.f, 1.f};
    float acc0, acc1, acc2, acc3;
    {
        const unsigned short* row = xp + (size_t)n * HID;
        uint2 rv = *(const uint2*)(row + 4 * l);
        acc0 = b2f_lo(rv.x);
        acc1 = b2f_hi(rv.x);
        acc2 = b2f_lo(rv.y);
        acc3 = b2f_hi(rv.y);
    }
    int ntile = (cnt + 63) >> 6;
    for (int tile = 0; tile < ntile; tile++) {
        int j = (tile << 6) + l;
        float4 lg = {-1e30f, -1e30f, -1e30f, -1e30f};
        int s = 0;
        if (j < cnt) {
            int2 a = adj[beg + j];
            s = a.x;
            float ea = __int_as_float(a.y);
            float4 as_ = a_s4[s];
            lg.x = lrelu(as_.x + adn.x + ea * wh.x);
            lg.y = lrelu(as_.y + adn.y + ea * wh.y);
            lg.z = lrelu(as_.z + adn.z + ea * wh.z);
            lg.w = lrelu(as_.w + adn.w + ea * wh.w);
        }
        float4 cm = lg;
        #pragma unroll
        for (int off = 32; off; off >>= 1) {
            cm.x = fmaxf(cm.x, __shfl_xor(cm.x, off));
            cm.y = fmaxf(cm.y, __shfl_xor(cm.y, off));
            cm.z = fmaxf(cm.z, __shfl_xor(cm.z, off));
            cm.w = fmaxf(cm.w, __shfl_xor(cm.w, off));
        }
        float4 mn;
        mn.x = fmaxf(m4.x, cm.x);
        mn.y = fmaxf(m4.y, cm.y);
        mn.z = fmaxf(m4.z, cm.z);
        mn.w = fmaxf(m4.w, cm.w);
        float4 sc;
        sc.x = __expf(m4.x - mn.x);
        sc.y = __expf(m4.y - mn.y);
        sc.z = __expf(m4.z - mn.z);
        sc.w = __expf(m4.w - mn.w);
        float4 p;
        p.x = __expf(lg.x - mn.x);
        p.y = __expf(lg.y - mn.y);
        p.z = __expf(lg.z - mn.z);
        p.w = __expf(lg.w - mn.w);
        m4 = mn;
        float4 ps = p;
        #pragma unroll
        for (int off = 32; off; off >>= 1) {
            ps.x += __shfl_xor(ps.x, off);
            ps.y += __shfl_xor(ps.y, off);
            ps.z += __shfl_xor(ps.z, off);
            ps.w += __shfl_xor(ps.w, off);
        }
        z4.x = z4.x * sc.x + ps.x;
        z4.y = z4.y * sc.y + ps.y;
        z4.z = z4.z * sc.z + ps.z;
        z4.w = z4.w * sc.w + ps.w;
        float scl = hl < 2 ? (hl == 0 ? sc.x : sc.y) : (hl == 2 ? sc.z : sc.w);
        acc0 *= scl;
        acc1 *= scl;
        acc2 *= scl;
        acc3 *= scl;
        sp[u][l] = p;
        ssrc[u][l] = s;
        int lim = min(64, cnt - (tile << 6));
        const float* spf = (const float*)&sp[u][0];
        int jj = 0;
        for (; jj + 2 <= lim; jj += 2) {
            int s0 = __builtin_amdgcn_readfirstlane(ssrc[u][jj]);
            int s1 = __builtin_amdgcn_readfirstlane(ssrc[u][jj + 1]);
            float p0 = spf[jj * 4 + hl];
            float p1 = spf[jj * 4 + 4 + hl];
            uint2 r0 = *(const uint2*)(xp + (size_t)s0 * HID + 4 * l);
            uint2 r1 = *(const uint2*)(xp + (size_t)s1 * HID + 4 * l);
            acc0 += p0 * b2f_lo(r0.x) + p1 * b2f_lo(r1.x);
            acc1 += p0 * b2f_hi(r0.x) + p1 * b2f_hi(r1.x);
            acc2 += p0 * b2f_lo(r0.y) + p1 * b2f_lo(r1.y);
            acc3 += p0 * b2f_hi(r0.y) + p1 * b2f_hi(r1.y);
        }
        if (jj < lim) {
            int s0 = __builtin_amdgcn_readfirstlane(ssrc[u][jj]);
            float p0 = spf[jj * 4 + hl];
            uint2 r0 = *(const uint2*)(xp + (size_t)s0 * HID + 4 * l);
            acc0 += p0 * b2f_lo(r0.x);
            acc1 += p0 * b2f_hi(r0.x);
            acc2 += p0 * b2f_lo(r0.y);
            acc3 += p0 * b2f_hi(r0.y);
        }
    }
    float zh = hl < 2 ? (hl == 0 ? z4.x : z4.y) : (hl == 2 ? z4.z : z4.w);
    float zi = 1.0f / (zh + 1e-16f);
    float4 bi = bias4[l];
    float v0 = acc0 * zi + bi.x;
    float v1 = acc1 * zi + bi.y;
    float v2 = acc2 * zi + bi.z;
    float v3 = acc3 * zi + bi.w;
    float s1 = v0 + v1 + v2 + v3;
    float s2 = v0 * v0 + v1 * v1 + v2 * v2 + v3 * v3;
    #pragma unroll
    for (int off = 32; off; off >>= 1) {
        s1 += __shfl_xor(s1, off);
        s2 += __shfl_xor(s2, off);
    }
    float mu = s1 * (1.0f / HID);
    float var = s2 * (1.0f / HID) - mu * mu;
    float rstd = rsqrtf(var + 1e-5f);
    float4 g = gamma4[l], be = beta4[l], xr = x4[(size_t)n * 64 + l];
    float4 o;
    o.x = (v0 - mu) * rstd * g.x + be.x + xr.x;
    o.y = (v1 - mu) * rstd * g.y + be.y + xr.y;
    o.z = (v2 - mu) * rstd * g.z + be.z + xr.z;
    o.w = (v3 - mu) * rstd * g.w + be.w + xr.w;
    o.x = o.x > 0.f ? o.x : 0.f;
    o.y = o.y > 0.f ? o.y : 0.f;
    o.z = o.z > 0.f ? o.z : 0.f;
    o.w = o.w > 0.f ? o.w : 0.f;
    out4[(size_t)n * 64 + l] = o;
}

extern "C" void kernel_launch(void* const* d_in, const int* in_sizes, int n_in,
                              void* d_out, int out_size, void* d_ws,
                              size_t ws_size, hipStream_t stream) {
    const float* x        = (const float*)d_in[0];
    const int*   ei       = (const int*)d_in[1];
    const float* eattr    = (const float*)d_in[2];
    const float* W        = (const float*)d_in[3];
    const float* att_src  = (const float*)d_in[4];
    const float* att_dst  = (const float*)d_in[5];
    const float* We       = (const float*)d_in[6];
    const float* att_edge = (const float*)d_in[7];
    const float* bias     = (const float*)d_in[8];
    const float* gamma    = (const float*)d_in[9];
    const float* beta     = (const float*)d_in[10];

    int N = in_sizes[0] / HID;
    int E = in_sizes[1] / 2;
    const int* src = ei;
    const int* dst = ei + E;

    // workspace layout (32-bit words, all 16B-aligned for N%4==0)
    float* base = (float*)d_ws;
    unsigned short* Ap = (unsigned short*)base;                      // N*128 w
    unsigned short* Bp = (unsigned short*)(base + (size_t)N * 128);  // 32768 w
    unsigned short* xp = (unsigned short*)(base + (size_t)N * 128 + 32768);
    float* a_s   = base + (size_t)N * 256 + 32768;                   // N*4
    float* a_d   = a_s + (size_t)N * 4;                              // N*4
    float* wedot = a_d + (size_t)N * 4;                              // 4
    // ---- zeroed region ----
    int* deg     = (int*)(wedot + 4);                                // N
    float* loopv = (float*)(deg + N);                                // N
    // ---- end zeroed ----
    int* rowptr  = (int*)(loopv + N);                                // N+4
    int* pos     = rowptr + N + 4;                                   // E
    int2* adj    = (int2*)(pos + E);                                 // E

    hipMemsetAsync(deg, 0, (size_t)2 * N * sizeof(int), stream);

    int XB = (N * 64 + 255) / 256;
    int DB = (E + 255) / 256;
    k_prep<<<XB + 65 + DB, 256, 0, stream>>>(x, W, We, att_edge, dst, eattr,
                                             Ap, Bp, wedot, deg, pos, loopv,
                                             N, E, XB);
    k_scan<<<1, 1024, 0, stream>>>(deg, rowptr, N);
    k_fill<<<(E + 255) / 256, 256, 0, stream>>>(src, dst, eattr, rowptr, pos,
                                                adj, E);
    int MF = (N + 15) / 16;
    k_mfma<<<(MF + 3) / 4, 256, 0, stream>>>(Ap, Bp, att_src, att_dst, xp, a_s,
                                             a_d, N, MF);
    k_gather_ln<<<(N + 3) / 4, 256, 0, stream>>>(
        adj, rowptr, (const float4*)a_s, (const float4*)a_d, wedot, deg, loopv,
        xp, (const float4*)x, (const float4*)bias, (const float4*)gamma,
        (const float4*)beta, (float4*)d_out, N);
}

// Round 6
// 107.183 us; speedup vs baseline: 4.7666x; 1.0032x over previous
//
#include <hip/hip_runtime.h>

#define HID 256
#define NH 4
#define NEG 0.2f

typedef __attribute__((ext_vector_type(8))) short short8;
typedef __attribute__((ext_vector_type(4))) float f32x4;

__device__ __forceinline__ unsigned short f2b(float f) {
    unsigned u = __float_as_uint(f);
    u = u + 0x7FFFu + ((u >> 16) & 1u);
    return (unsigned short)(u >> 16);
}
__device__ __forceinline__ float b2f_lo(unsigned u) {
    return __uint_as_float(u << 16);
}
__device__ __forceinline__ float b2f_hi(unsigned u) {
    return __uint_as_float(u & 0xFFFF0000u);
}
__device__ __forceinline__ float lrelu(float f) {
    return f > 0.f ? f : NEG * f;
}

// ---- K_prep: [x->Ap pack (LDS-staged) | W->Bp pack (LDS-staged) | wedot |
//               deg count (non-returning atomic)] ----
// frag layout: Ap[((fi*8+ks)*64+lane)*8+j] = A[fi*16+(lane&15)][ks*32+(lane>>4)*8+j]
__global__ __launch_bounds__(256) void k_prep(
    const float* __restrict__ x, const float* __restrict__ W,
    const float* __restrict__ We, const float* __restrict__ att_edge,
    const int* __restrict__ dst,
    unsigned short* __restrict__ Ap, unsigned short* __restrict__ Bp,
    float* __restrict__ wedot, int* __restrict__ deg, int N, int E, int XB) {
    __shared__ unsigned short sm[4096];
    int b = blockIdx.x, t = threadIdx.x;
    if (b < XB) {  // ---- pack x: one 16-row tile -> 8KB contiguous ----
        int fi = b;
        int r = t >> 4;             // row in tile
        int row = fi * 16 + r;
        const float4* x4 = (const float4*)x;
        #pragma unroll
        for (int q = 0; q < 4; q++) {
            int c4 = (t & 15) + (q << 4);   // float4 col index 0..63
            unsigned u0 = 0, u1 = 0;
            if (row < N) {
                float4 v = x4[(size_t)row * 64 + c4];
                u0 = (unsigned)f2b(v.x) | ((unsigned)f2b(v.y) << 16);
                u1 = (unsigned)f2b(v.z) | ((unsigned)f2b(v.w) << 16);
            }
            int k0 = c4 << 2;
            int ks = k0 >> 5, ko = k0 & 31;
            int lane = r + ((ko >> 3) << 4);
            int off = ks * 512 + lane * 8 + (ko & 7);
            *((uint2*)&sm[off]) = make_uint2(u0, u1);
        }
        __syncthreads();
        uint4* out = (uint4*)(Ap + (size_t)fi * 4096);
        const uint4* smv = (const uint4*)sm;
        out[t] = smv[t];
        out[256 + t] = smv[256 + t];
    } else if (b < XB + 16) {  // ---- pack W: one 16-col strip ----
        int n16 = b - XB;
        int k = t;
        int ks = k >> 5;
        int lhi = ((k & 31) >> 3) << 4;
        int j = k & 7;
        const float4* W4 = (const float4*)W;
        #pragma unroll
        for (int q = 0; q < 4; q++) {
            float4 v = W4[(size_t)k * 64 + n16 * 4 + q];
            int c = q << 2;
            sm[ks * 512 + (lhi + c + 0) * 8 + j] = f2b(v.x);
            sm[ks * 512 + (lhi + c + 1) * 8 + j] = f2b(v.y);
            sm[ks * 512 + (lhi + c + 2) * 8 + j] = f2b(v.z);
            sm[ks * 512 + (lhi + c + 3) * 8 + j] = f2b(v.w);
        }
        __syncthreads();
        uint4* out = (uint4*)(Bp + (size_t)n16 * 4096);
        const uint4* smv = (const uint4*)sm;
        out[t] = smv[t];
        out[256 + t] = smv[256 + t];
    } else if (b == XB + 16) {  // ---- wedot ----
        float v = We[t] * att_edge[t];
        #pragma unroll
        for (int off = 32; off; off >>= 1) v += __shfl_down(v, off);
        if ((t & 63) == 0) wedot[t >> 6] = v;
    } else {  // ---- degree count (fire-and-forget) ----
        int e = (b - XB - 17) * 256 + t;
        if (e < E) atomicAdd(&deg[dst[e]], 1);
    }
}

// ---- K_scan: exclusive prefix scan of deg -> rowptr + cursor init ----
__global__ __launch_bounds__(1024) void k_scan(const int* __restrict__ deg,
                                               int* __restrict__ rowptr,
                                               int* __restrict__ cursor,
                                               int N) {
    __shared__ int wsum[16], woff[16];
    int t = threadIdx.x, lane = t & 63, w = t >> 6;
    int base = t * 10;
    int d[10], s = 0;
    #pragma unroll
    for (int u = 0; u < 10; u++) {
        int i = base + u;
        int v = (i < N) ? deg[i] : 0;
        d[u] = v;
        s += v;
    }
    int incl = s;
    #pragma unroll
    for (int off = 1; off < 64; off <<= 1) {
        int up = __shfl_up(incl, off);
        if (lane >= off) incl += up;
    }
    if (lane == 63) wsum[w] = incl;
    __syncthreads();
    if (t < 16) {
        int v = wsum[t];
        int inc = v;
        #pragma unroll
        for (int off = 1; off < 16; off <<= 1) {
            int up = __shfl_up(inc, off);
            if (t >= off) inc += up;
        }
        woff[t] = inc - v;
    }
    __syncthreads();
    int run = woff[w] + (incl - s);
    #pragma unroll
    for (int u = 0; u < 10; u++) {
        int i = base + u;
        if (i < N) {
            rowptr[i] = run;
            cursor[i] = run;
            run += d[u];
        }
    }
    if (base < N && base + 10 >= N) rowptr[N] = run;
}

// ---- K_fill: slot capture + scatter write, 2 edges/thread ----
__global__ void k_fill(const int* __restrict__ src, const int* __restrict__ dst,
                       const float* __restrict__ eattr,
                       int* __restrict__ cursor, int2* __restrict__ adj,
                       int E) {
    int e0 = blockIdx.x * 512 + threadIdx.x;
    int e1 = e0 + 256;
    int s0 = 0, s1 = 0, d0 = 0, d1 = 0;
    float a0 = 0.f, a1 = 0.f;
    if (e0 < E) { s0 = src[e0]; d0 = dst[e0]; a0 = eattr[e0]; }
    if (e1 < E) { s1 = src[e1]; d1 = dst[e1]; a1 = eattr[e1]; }
    int p0 = 0, p1 = 0;
    if (e0 < E) p0 = atomicAdd(&cursor[d0], 1);
    if (e1 < E) p1 = atomicAdd(&cursor[d1], 1);
    if (e0 < E) adj[p0] = make_int2(s0, __float_as_int(a0));
    if (e1 < E) adj[p1] = make_int2(s1, __float_as_int(a1));
}

// ---- K_mfma: xp = x@W via bf16 MFMA, fused a_s/a_d epilogue ----
__global__ __launch_bounds__(256) void k_mfma(
    const unsigned short* __restrict__ Ap, const unsigned short* __restrict__ Bp,
    const float* __restrict__ att_src, const float* __restrict__ att_dst,
    unsigned short* __restrict__ xp, float* __restrict__ a_s,
    float* __restrict__ a_d, int N, int MF) {
    int t = threadIdx.x, w = t >> 6, l = t & 63;
    int fi0 = blockIdx.x * 4;
    const short8* A8 = (const short8*)Ap;
    const short8* B8 = (const short8*)Bp;
    f32x4 acc[4][4];
    #pragma unroll
    for (int mi = 0; mi < 4; mi++)
        #pragma unroll
        for (int ni = 0; ni < 4; ni++)
            acc[mi][ni] = (f32x4){0.f, 0.f, 0.f, 0.f};
    short8 zz = {0, 0, 0, 0, 0, 0, 0, 0};
    #pragma unroll
    for (int ks = 0; ks < 8; ks++) {
        short8 a[4], b[4];
        #pragma unroll
        for (int mi = 0; mi < 4; mi++) {
            int fi = fi0 + mi;
            a[mi] = (fi < MF) ? A8[(size_t)(fi * 8 + ks) * 64 + l] : zz;
        }
        #pragma unroll
        for (int ni = 0; ni < 4; ni++)
            b[ni] = B8[(size_t)(((w << 2) + ni) * 8 + ks) * 64 + l];
        #pragma unroll
        for (int mi = 0; mi < 4; mi++)
            #pragma unroll
            for (int ni = 0; ni < 4; ni++)
                acc[mi][ni] = __builtin_amdgcn_mfma_f32_16x16x32_bf16(
                    a[mi], b[ni], acc[mi][ni], 0, 0, 0);
    }
    int colb = w << 6;
    float asc[4], adc[4];
    #pragma unroll
    for (int ni = 0; ni < 4; ni++) {
        asc[ni] = att_src[colb + ni * 16 + (l & 15)];
        adc[ni] = att_dst[colb + ni * 16 + (l & 15)];
    }
    #pragma unroll
    for (int mi = 0; mi < 4; mi++) {
        int rowb = fi0 * 16 + mi * 16 + ((l >> 4) << 2);
        #pragma unroll
        for (int r = 0; r < 4; r++) {
            int row = rowb + r;
            float ps = 0.f, pd = 0.f;
            #pragma unroll
            for (int ni = 0; ni < 4; ni++) {
                float v = acc[mi][ni][r];
                ps += v * asc[ni];
                pd += v * adc[ni];
            }
            #pragma unroll
            for (int off = 1; off < 16; off <<= 1) {
                ps += __shfl_xor(ps, off);
                pd += __shfl_xor(pd, off);
            }
            if (row < N) {
                if ((l & 15) == 0) {
                    a_s[(row << 2) + w] = ps;
                    a_d[(row << 2) + w] = pd;
                }
                #pragma unroll
                for (int ni = 0; ni < 4; ni++)
                    xp[(size_t)row * HID + colb + ni * 16 + (l & 15)] =
                        f2b(acc[mi][ni][r]);
            }
        }
    }
}

// ---- K_gather_ln: wave-per-node online-softmax gather; self-loop folded
//      in at the end (loop_ea computed from the edges themselves) ----
__global__ __launch_bounds__(256) void k_gather_ln(
    const int2* __restrict__ adj, const int* __restrict__ rowptr,
    const float4* __restrict__ a_s4, const float4* __restrict__ a_d4,
    const float* __restrict__ wedot, const unsigned short* __restrict__ xp,
    const float4* __restrict__ x4, const float4* __restrict__ bias4,
    const float4* __restrict__ gamma4, const float4* __restrict__ beta4,
    float4* __restrict__ out4, int N) {
    __shared__ float4 sp[4][64];
    __shared__ int ssrc[4][64];
    int t = threadIdx.x;
    int u = t >> 6, l = t & 63, hl = l >> 4;
    int n = blockIdx.x * 4 + u;
    if (n >= N) return;
    int beg = rowptr[n], cnt = rowptr[n + 1] - beg;
    float4 adn = a_d4[n];
    float4 wh = *(const float4*)wedot;
    float4 m4 = {-1e30f, -1e30f, -1e30f, -1e30f};
    float4 z4 = {0.f, 0.f, 0.f, 0.f};
    float acc0 = 0.f, acc1 = 0.f, acc2 = 0.f, acc3 = 0.f;
    float se = 0.f;
    int ntile = (cnt + 63) >> 6;
    for (int tile = 0; tile < ntile; tile++) {
        int j = (tile << 6) + l;
        float4 lg = {-1e30f, -1e30f, -1e30f, -1e30f};
        float ea = 0.f;
        int s = 0;
        if (j < cnt) {
            int2 a = adj[beg + j];
            s = a.x;
            ea = __int_as_float(a.y);
            float4 as_ = a_s4[s];
            lg.x = lrelu(as_.x + adn.x + ea * wh.x);
            lg.y = lrelu(as_.y + adn.y + ea * wh.y);
            lg.z = lrelu(as_.z + adn.z + ea * wh.z);
            lg.w = lrelu(as_.w + adn.w + ea * wh.w);
        }
        float4 cm = lg;
        float es = ea;
        #pragma unroll
        for (int off = 32; off; off >>= 1) {
            cm.x = fmaxf(cm.x, __shfl_xor(cm.x, off));
            cm.y = fmaxf(cm.y, __shfl_xor(cm.y, off));
            cm.z = fmaxf(cm.z, __shfl_xor(cm.z, off));
            cm.w = fmaxf(cm.w, __shfl_xor(cm.w, off));
            es += __shfl_xor(es, off);
        }
        se += es;
        float4 mn;
        mn.x = fmaxf(m4.x, cm.x);
        mn.y = fmaxf(m4.y, cm.y);
        mn.z = fmaxf(m4.z, cm.z);
        mn.w = fmaxf(m4.w, cm.w);
        float4 sc;
        sc.x = __expf(m4.x - mn.x);
        sc.y = __expf(m4.y - mn.y);
        sc.z = __expf(m4.z - mn.z);
        sc.w = __expf(m4.w - mn.w);
        float4 p;
        p.x = __expf(lg.x - mn.x);
        p.y = __expf(lg.y - mn.y);
        p.z = __expf(lg.z - mn.z);
        p.w = __expf(lg.w - mn.w);
        m4 = mn;
        float4 ps = p;
        #pragma unroll
        for (int off = 32; off; off >>= 1) {
            ps.x += __shfl_xor(ps.x, off);
            ps.y += __shfl_xor(ps.y, off);
            ps.z += __shfl_xor(ps.z, off);
            ps.w += __shfl_xor(ps.w, off);
        }
        z4.x = z4.x * sc.x + ps.x;
        z4.y = z4.y * sc.y + ps.y;
        z4.z = z4.z * sc.z + ps.z;
        z4.w = z4.w * sc.w + ps.w;
        float scl = hl < 2 ? (hl == 0 ? sc.x : sc.y) : (hl == 2 ? sc.z : sc.w);
        acc0 *= scl;
        acc1 *= scl;
        acc2 *= scl;
        acc3 *= scl;
        sp[u][l] = p;
        ssrc[u][l] = s;
        int lim = min(64, cnt - (tile << 6));
        const float* spf = (const float*)&sp[u][0];
        int jj = 0;
        for (; jj + 2 <= lim; jj += 2) {
            int s0 = __builtin_amdgcn_readfirstlane(ssrc[u][jj]);
            int s1 = __builtin_amdgcn_readfirstlane(ssrc[u][jj + 1]);
            float p0 = spf[jj * 4 + hl];
            float p1 = spf[jj * 4 + 4 + hl];
            uint2 r0 = *(const uint2*)(xp + (size_t)s0 * HID + 4 * l);
            uint2 r1 = *(const uint2*)(xp + (size_t)s1 * HID + 4 * l);
            acc0 += p0 * b2f_lo(r0.x) + p1 * b2f_lo(r1.x);
            acc1 += p0 * b2f_hi(r0.x) + p1 * b2f_hi(r1.x);
            acc2 += p0 * b2f_lo(r0.y) + p1 * b2f_lo(r1.y);
            acc3 += p0 * b2f_hi(r0.y) + p1 * b2f_hi(r1.y);
        }
        if (jj < lim) {
            int s0 = __builtin_amdgcn_readfirstlane(ssrc[u][jj]);
            float p0 = spf[jj * 4 + hl];
            uint2 r0 = *(const uint2*)(xp + (size_t)s0 * HID + 4 * l);
            acc0 += p0 * b2f_lo(r0.x);
            acc1 += p0 * b2f_hi(r0.x);
            acc2 += p0 * b2f_lo(r0.y);
            acc3 += p0 * b2f_hi(r0.y);
        }
    }
    // ---- fold in self-loop: ea_self = mean incoming eattr ----
    {
        float loop_ea = se / fmaxf((float)cnt, 1.0f);
        float4 asn = a_s4[n];
        float4 lgs;
        lgs.x = lrelu(asn.x + adn.x + loop_ea * wh.x);
        lgs.y = lrelu(asn.y + adn.y + loop_ea * wh.y);
        lgs.z = lrelu(asn.z + adn.z + loop_ea * wh.z);
        lgs.w = lrelu(asn.w + adn.w + loop_ea * wh.w);
        float4 mn;
        mn.x = fmaxf(m4.x, lgs.x);
        mn.y = fmaxf(m4.y, lgs.y);
        mn.z = fmaxf(m4.z, lgs.z);
        mn.w = fmaxf(m4.w, lgs.w);
        float4 so;
        so.x = __expf(m4.x - mn.x);
        so.y = __expf(m4.y - mn.y);
        so.z = __expf(m4.z - mn.z);
        so.w = __expf(m4.w - mn.w);
        float4 pf;
        pf.x = __expf(lgs.x - mn.x);
        pf.y = __expf(lgs.y - mn.y);
        pf.z = __expf(lgs.z - mn.z);
        pf.w = __expf(lgs.w - mn.w);
        z4.x = z4.x * so.x + pf.x;
        z4.y = z4.y * so.y + pf.y;
        z4.z = z4.z * so.z + pf.z;
        z4.w = z4.w * so.w + pf.w;
        float sol = hl < 2 ? (hl == 0 ? so.x : so.y) : (hl == 2 ? so.z : so.w);
        float psl = hl < 2 ? (hl == 0 ? pf.x : pf.y) : (hl == 2 ? pf.z : pf.w);
        uint2 rv = *(const uint2*)(xp + (size_t)n * HID + 4 * l);
        acc0 = acc0 * sol + psl * b2f_lo(rv.x);
        acc1 = acc1 * sol + psl * b2f_hi(rv.x);
        acc2 = acc2 * sol + psl * b2f_lo(rv.y);
        acc3 = acc3 * sol + psl * b2f_hi(rv.y);
    }
    float zh = hl < 2 ? (hl == 0 ? z4.x : z4.y) : (hl == 2 ? z4.z : z4.w);
    float zi = 1.0f / (zh + 1e-16f);
    float4 bi = bias4[l];
    float v0 = acc0 * zi + bi.x;
    float v1 = acc1 * zi + bi.y;
    float v2 = acc2 * zi + bi.z;
    float v3 = acc3 * zi + bi.w;
    float s1 = v0 + v1 + v2 + v3;
    float s2 = v0 * v0 + v1 * v1 + v2 * v2 + v3 * v3;
    #pragma unroll
    for (int off = 32; off; off >>= 1) {
        s1 += __shfl_xor(s1, off);
        s2 += __shfl_xor(s2, off);
    }
    float mu = s1 * (1.0f / HID);
    float var = s2 * (1.0f / HID) - mu * mu;
    float rstd = rsqrtf(var + 1e-5f);
    float4 g = gamma4[l], be = beta4[l], xr = x4[(size_t)n * 64 + l];
    float4 o;
    o.x = (v0 - mu) * rstd * g.x + be.x + xr.x;
    o.y = (v1 - mu) * rstd * g.y + be.y + xr.y;
    o.z = (v2 - mu) * rstd * g.z + be.z + xr.z;
    o.w = (v3 - mu) * rstd * g.w + be.w + xr.w;
    o.x = o.x > 0.f ? o.x : 0.f;
    o.y = o.y > 0.f ? o.y : 0.f;
    o.z = o.z > 0.f ? o.z : 0.f;
    o.w = o.w > 0.f ? o.w : 0.f;
    out4[(size_t)n * 64 + l] = o;
}

extern "C" void kernel_launch(void* const* d_in, const int* in_sizes, int n_in,
                              void* d_out, int out_size, void* d_ws,
                              size_t ws_size, hipStream_t stream) {
    const float* x        = (const float*)d_in[0];
    const int*   ei       = (const int*)d_in[1];
    const float* eattr    = (const float*)d_in[2];
    const float* W        = (const float*)d_in[3];
    const float* att_src  = (const float*)d_in[4];
    const float* att_dst  = (const float*)d_in[5];
    const float* We       = (const float*)d_in[6];
    const float* att_edge = (const float*)d_in[7];
    const float* bias     = (const float*)d_in[8];
    const float* gamma    = (const float*)d_in[9];
    const float* beta     = (const float*)d_in[10];

    int N = in_sizes[0] / HID;
    int E = in_sizes[1] / 2;
    const int* src = ei;
    const int* dst = ei + E;

    int MF = (N + 15) / 16;
    size_t NP = (size_t)MF * 16;

    // workspace layout (32-bit words)
    float* base = (float*)d_ws;
    unsigned short* Ap = (unsigned short*)base;                    // NP*128 w
    unsigned short* Bp = (unsigned short*)(base + NP * 128);       // 32768 w
    unsigned short* xp = (unsigned short*)(base + NP * 128 + 32768);  // NP*128
    float* a_s   = base + NP * 256 + 32768;                        // N*4
    float* a_d   = a_s + (size_t)N * 4;                            // N*4
    float* wedot = a_d + (size_t)N * 4;                            // 4
    int* deg     = (int*)(wedot + 4);                              // N (zeroed)
    int* cursor  = deg + N;                                        // N
    int* rowptr  = cursor + N;                                     // N+4
    int2* adj    = (int2*)(rowptr + N + 4);                        // E

    hipMemsetAsync(deg, 0, (size_t)N * sizeof(int), stream);

    int XB = MF;
    int DB = (E + 255) / 256;
    k_prep<<<XB + 17 + DB, 256, 0, stream>>>(x, W, We, att_edge, dst, Ap, Bp,
                                             wedot, deg, N, E, XB);
    k_scan<<<1, 1024, 0, stream>>>(deg, rowptr, cursor, N);
    k_fill<<<(E + 511) / 512, 256, 0, stream>>>(src, dst, eattr, cursor, adj,
                                                E);
    k_mfma<<<(MF + 3) / 4, 256, 0, stream>>>(Ap, Bp, att_src, att_dst, xp, a_s,
                                             a_d, N, MF);
    k_gather_ln<<<(N + 3) / 4, 256, 0, stream>>>(
        adj, rowptr, (const float4*)a_s, (const float4*)a_d, wedot, xp,
        (const float4*)x, (const float4*)bias, (const float4*)gamma,
        (const float4*)beta, (float4*)d_out, N);
}